// Round 2
// baseline (462.575 us; speedup 1.0000x reference)
//
#include <hip/hip_runtime.h>
#include <hip/hip_bf16.h>

#define T_TOK 8192
#define DDIM  1024
#define HDIM  4096
#define KCAT  8192   // 2*HDIM
#define NE    8

typedef __attribute__((ext_vector_type(8))) __bf16 bf16x8;
typedef __attribute__((ext_vector_type(4))) float  f32x4;

__device__ __forceinline__ unsigned short f2bf(float f) {
  union { float f; unsigned u; } v; v.f = f;
  unsigned r = v.u + 0x7fffu + ((v.u >> 16) & 1u);
  return (unsigned short)(r >> 16);
}

__device__ __forceinline__ void gl_lds16(const unsigned short* g, char* l) {
  __builtin_amdgcn_global_load_lds(
      (__attribute__((address_space(1))) const void*)g,
      (__attribute__((address_space(3))) void*)l,
      16, 0, 0);
}

// ---------------- router + x -> bf16 conversion ----------------
// one wave per token; 4 waves per block
__global__ __launch_bounds__(256) void k_router(
    const float* __restrict__ x, const float* __restrict__ Wr,
    const float* __restrict__ br, unsigned short* __restrict__ xb,
    float* __restrict__ gates)
{
  const int lane = threadIdx.x & 63;
  const int wv   = threadIdx.x >> 6;
  const int t    = blockIdx.x * 4 + wv;
  const float* xr = x + (size_t)t * DDIM;
  unsigned short* xo = xb + (size_t)t * DDIM;

  float acc[NE];
#pragma unroll
  for (int e = 0; e < NE; ++e) acc[e] = 0.f;

#pragma unroll
  for (int i = 0; i < 4; ++i) {
    float4 v = *(const float4*)(xr + i * 256 + lane * 4);
    ushort4 o;
    o.x = f2bf(v.x); o.y = f2bf(v.y); o.z = f2bf(v.z); o.w = f2bf(v.w);
    *(ushort4*)(xo + i * 256 + lane * 4) = o;
    float vs[4] = {v.x, v.y, v.z, v.w};
#pragma unroll
    for (int j = 0; j < 4; ++j) {
      const float4* wr = (const float4*)(Wr + (size_t)(i * 256 + lane * 4 + j) * NE);
      float4 w0 = wr[0], w1 = wr[1];
      acc[0] += vs[j] * w0.x; acc[1] += vs[j] * w0.y;
      acc[2] += vs[j] * w0.z; acc[3] += vs[j] * w0.w;
      acc[4] += vs[j] * w1.x; acc[5] += vs[j] * w1.y;
      acc[6] += vs[j] * w1.z; acc[7] += vs[j] * w1.w;
    }
  }
#pragma unroll
  for (int e = 0; e < NE; ++e) {
#pragma unroll
    for (int s = 32; s > 0; s >>= 1) acc[e] += __shfl_xor(acc[e], s, 64);
  }
  if (lane == 0) {
    float lg[NE];
#pragma unroll
    for (int e = 0; e < NE; ++e) lg[e] = acc[e] + br[e];
    int a1 = 0; float m1 = lg[0];
#pragma unroll
    for (int e = 1; e < NE; ++e) if (lg[e] > m1) { m1 = lg[e]; a1 = e; }
    float m2 = -3.4e38f;
#pragma unroll
    for (int e = 0; e < NE; ++e) if (e != a1 && lg[e] > m2) m2 = lg[e];
    float g0 = 1.f / (1.f + expf(m2 - m1));  // = p1/(p1+p2) after softmax+renorm
    gates[t * 2 + 0] = g0;
    gates[t * 2 + 1] = 1.f - g0;
  }
}

// ---------------- fp32 -> bf16 transpose (per expert z) ----------------
// out[c*S + r] = bf16(in[r*C + c]);  in/out advanced by z*inz / z*outz
__global__ __launch_bounds__(256) void k_transpose(
    const float* __restrict__ in, unsigned short* __restrict__ out,
    int R, int C, int S, size_t inz, size_t outz)
{
  __shared__ float tile[32][33];
  in  += (size_t)blockIdx.z * inz;
  out += (size_t)blockIdx.z * outz;
  const int c0 = blockIdx.x * 32, r0 = blockIdx.y * 32;
  const int tx = threadIdx.x & 31, ty = threadIdx.x >> 5;
#pragma unroll
  for (int i = 0; i < 32; i += 8)
    tile[ty + i][tx] = in[(size_t)(r0 + ty + i) * C + (c0 + tx)];
  __syncthreads();
#pragma unroll
  for (int i = 0; i < 32; i += 8)
    out[(size_t)(c0 + ty + i) * S + (r0 + tx)] = f2bf(tile[tx][ty + i]);
}

// ---------------- tiled MFMA GEMM ----------------
// C[M][N] = A[M][KL] * B[N][KL]^T   (A row-major, B given transposed: [N][KL])
// Block tile BM x 128, BK=32, 4 waves (2x2), each wave (BM/2) x 64.
// MODE 0: layer1 -> h' = bf16(gate_e * relu(acc + b1[e][col])), col base e*HDIM
// MODE 1: layer2 -> out fp32 = acc + g0*b2[0][col] + g1*b2[1][col]
template<int BM, int MODE, int KL>
__global__ __launch_bounds__(256) void k_gemm(
    const unsigned short* __restrict__ A,
    const unsigned short* __restrict__ B,
    void* __restrict__ Cout,
    const float* __restrict__ bias,
    const float* __restrict__ gates)
{
  constexpr int MI     = BM / 32;        // 16x16 frags per wave along M
  constexpr int ABYTES = BM * 64;        // A tile bytes (BM rows x 32k x 2B)
  __shared__ __align__(16) char lds[2][(BM + 128) * 64];

  const int tid = threadIdx.x;
  const int w   = tid >> 6;
  const int l   = tid & 63;
  const int g   = l >> 4;
  const int l15 = l & 15;

  const int bn = blockIdx.x * 128;
  const int bm = blockIdx.y * BM;
  const int e  = (MODE == 0) ? blockIdx.z : 0;

  const unsigned short* Ab = A + (size_t)bm * KL;
  const unsigned short* Bb = B + (size_t)e * ((size_t)HDIM * DDIM) + (size_t)bn * KL;

  // staging: per global_load_lds instr, 64 lanes = 16 rows x 4 16B-chunks.
  // swizzled chunk so that frag ds_read_b128 is bank-conflict-free:
  // LDS slot (r, c) holds global chunk (r, c ^ ((r>>1)&3))
  const int sr = l >> 2;                          // row within 16-row group
  const int sc = (l & 3) ^ ((l >> 3) & 3);        // swizzled source chunk

  // fragment read offsets (bytes within current buffer)
  int a_off[MI], b_off[4];
#pragma unroll
  for (int mi = 0; mi < MI; ++mi) {
    int m = (w >> 1) * (BM / 2) + mi * 16 + l15;
    a_off[mi] = m * 64 + ((g ^ ((m >> 1) & 3)) * 16);
  }
#pragma unroll
  for (int nj = 0; nj < 4; ++nj) {
    int n = (w & 1) * 64 + nj * 16 + l15;
    b_off[nj] = ABYTES + n * 64 + ((g ^ ((n >> 1) & 3)) * 16);
  }

  auto stage = [&](char* buf, int k0) {
#pragma unroll
    for (int qq = 0; qq < BM / 64; ++qq) {
      int q = w + qq * 4;
      gl_lds16(Ab + (size_t)(q * 16 + sr) * KL + k0 + sc * 8, buf + q * 1024);
    }
#pragma unroll
    for (int qq = 0; qq < 2; ++qq) {
      int q = w + qq * 4;
      gl_lds16(Bb + (size_t)(q * 16 + sr) * KL + k0 + sc * 8, buf + ABYTES + q * 1024);
    }
  };

  f32x4 acc[MI][4];
#pragma unroll
  for (int mi = 0; mi < MI; ++mi)
#pragma unroll
    for (int nj = 0; nj < 4; ++nj)
      acc[mi][nj] = (f32x4){0.f, 0.f, 0.f, 0.f};

  constexpr int NT = KL / 32;
  stage(lds[0], 0);
  __syncthreads();
  int cur = 0;
  for (int t = 0; t < NT; ++t) {
    if (t + 1 < NT) stage(lds[cur ^ 1], (t + 1) * 32);
    const char* ls = lds[cur];
    bf16x8 af[MI], bfr[4];
#pragma unroll
    for (int mi = 0; mi < MI; ++mi) af[mi] = *(const bf16x8*)(ls + a_off[mi]);
#pragma unroll
    for (int nj = 0; nj < 4; ++nj) bfr[nj] = *(const bf16x8*)(ls + b_off[nj]);
#pragma unroll
    for (int mi = 0; mi < MI; ++mi)
#pragma unroll
      for (int nj = 0; nj < 4; ++nj)
        acc[mi][nj] = __builtin_amdgcn_mfma_f32_16x16x32_bf16(af[mi], bfr[nj], acc[mi][nj], 0, 0, 0);
    __syncthreads();
    cur ^= 1;
  }

  // C/D frag map: col = l&15, row = (l>>4)*4 + r
  if (MODE == 0) {
    unsigned short* H = (unsigned short*)Cout;
    float b1v[4];
#pragma unroll
    for (int nj = 0; nj < 4; ++nj)
      b1v[nj] = bias[e * HDIM + bn + (w & 1) * 64 + nj * 16 + l15];
#pragma unroll
    for (int mi = 0; mi < MI; ++mi) {
#pragma unroll
      for (int r = 0; r < 4; ++r) {
        int t = bm + (w >> 1) * (BM / 2) + mi * 16 + g * 4 + r;
        float gate = gates[t * 2 + e];
        size_t rowb = (size_t)t * KCAT + e * HDIM + bn + (w & 1) * 64 + l15;
#pragma unroll
        for (int nj = 0; nj < 4; ++nj) {
          float v = acc[mi][nj][r] + b1v[nj];
          v = fmaxf(v, 0.f) * gate;
          H[rowb + nj * 16] = f2bf(v);
        }
      }
    }
  } else {
    float* O = (float*)Cout;
    float b20[4], b21[4];
#pragma unroll
    for (int nj = 0; nj < 4; ++nj) {
      int col = bn + (w & 1) * 64 + nj * 16 + l15;
      b20[nj] = bias[col];
      b21[nj] = bias[DDIM + col];
    }
#pragma unroll
    for (int mi = 0; mi < MI; ++mi) {
#pragma unroll
      for (int r = 0; r < 4; ++r) {
        int t = bm + (w >> 1) * (BM / 2) + mi * 16 + g * 4 + r;
        float g0 = gates[t * 2 + 0], g1 = gates[t * 2 + 1];
        size_t rowb = (size_t)t * DDIM + bn + (w & 1) * 64 + l15;
#pragma unroll
        for (int nj = 0; nj < 4; ++nj)
          O[rowb + nj * 16] = acc[mi][nj][r] + g0 * b20[nj] + g1 * b21[nj];
      }
    }
  }
}

extern "C" void kernel_launch(void* const* d_in, const int* in_sizes, int n_in,
                              void* d_out, int out_size, void* d_ws, size_t ws_size,
                              hipStream_t stream) {
  const float* x  = (const float*)d_in[0];
  const float* Wr = (const float*)d_in[1];
  const float* br = (const float*)d_in[2];
  const float* W1 = (const float*)d_in[3];
  const float* b1 = (const float*)d_in[4];
  const float* W2 = (const float*)d_in[5];
  const float* b2 = (const float*)d_in[6];

  char* ws = (char*)d_ws;
  unsigned short* xb    = (unsigned short*)(ws);                       // 16 MB  x bf16 [8192][1024]
  unsigned short* W1T   = (unsigned short*)(ws + (16u << 20));         // 16 MB  [2][4096][1024]
  unsigned short* W2T   = (unsigned short*)(ws + (32u << 20));         // 16 MB  [1024][8192] concat
  float*          gates = (float*)(ws + (48u << 20));                  // 64 KB  [8192][2]
  unsigned short* hbuf  = (unsigned short*)(ws + (49u << 20));         // 128 MB [8192][8192]

  // 1) router + x->bf16
  k_router<<<dim3(T_TOK / 4), dim3(256), 0, stream>>>(x, Wr, br, xb, gates);

  // 2) W1[e][d][h] -> W1T[e][h][d]   (R=D rows, C=H cols)
  k_transpose<<<dim3(HDIM / 32, DDIM / 32, 2), dim3(256), 0, stream>>>(
      W1, W1T, DDIM, HDIM, DDIM, (size_t)DDIM * HDIM, (size_t)HDIM * DDIM);

  // 3) W2[e][h][d] -> W2T[d][e*HDIM + h]  (R=H rows, C=D cols, out stride KCAT)
  k_transpose<<<dim3(DDIM / 32, HDIM / 32, 2), dim3(256), 0, stream>>>(
      W2, W2T, HDIM, DDIM, KCAT, (size_t)HDIM * DDIM, (size_t)HDIM);

  // 4) layer1: h'[t][e*4096+h] = bf16(gate_e[t] * relu(x@W1[e] + b1[e]))
  k_gemm<128, 0, DDIM><<<dim3(HDIM / 128, T_TOK / 128, 2), dim3(256), 0, stream>>>(
      xb, W1T, (void*)hbuf, b1, gates);

  // 5) layer2: out[t][d] = h'@W2Tcat + g0*b2[0][d] + g1*b2[1][d]
  k_gemm<64, 1, KCAT><<<dim3(DDIM / 128, T_TOK / 64, 1), dim3(256), 0, stream>>>(
      hbuf, W2T, d_out, b2, gates);
}

// Round 3
// 333.032 us; speedup vs baseline: 1.3890x; 1.3890x over previous
//
#include <hip/hip_runtime.h>
#include <hip/hip_bf16.h>

#define T_TOK 8192
#define DDIM  1024
#define HDIM  4096
#define KCAT  8192   // 2*HDIM
#define NE    8

typedef __attribute__((ext_vector_type(8))) __bf16 bf16x8;
typedef __attribute__((ext_vector_type(4))) float  f32x4;

__device__ __forceinline__ unsigned short f2bf(float f) {
  union { float f; unsigned u; } v; v.f = f;
  unsigned r = v.u + 0x7fffu + ((v.u >> 16) & 1u);
  return (unsigned short)(r >> 16);
}

__device__ __forceinline__ void gl_lds16(const unsigned short* g, char* l) {
  __builtin_amdgcn_global_load_lds(
      (__attribute__((address_space(1))) const void*)g,
      (__attribute__((address_space(3))) void*)l,
      16, 0, 0);
}

// ---------------- router + x -> bf16 conversion ----------------
__global__ __launch_bounds__(256) void k_router(
    const float* __restrict__ x, const float* __restrict__ Wr,
    const float* __restrict__ br, unsigned short* __restrict__ xb,
    float* __restrict__ gates)
{
  const int lane = threadIdx.x & 63;
  const int wv   = threadIdx.x >> 6;
  const int t    = blockIdx.x * 4 + wv;
  const float* xr = x + (size_t)t * DDIM;
  unsigned short* xo = xb + (size_t)t * DDIM;

  float acc[NE];
#pragma unroll
  for (int e = 0; e < NE; ++e) acc[e] = 0.f;

#pragma unroll
  for (int i = 0; i < 4; ++i) {
    float4 v = *(const float4*)(xr + i * 256 + lane * 4);
    ushort4 o;
    o.x = f2bf(v.x); o.y = f2bf(v.y); o.z = f2bf(v.z); o.w = f2bf(v.w);
    *(ushort4*)(xo + i * 256 + lane * 4) = o;
    float vs[4] = {v.x, v.y, v.z, v.w};
#pragma unroll
    for (int j = 0; j < 4; ++j) {
      const float4* wr = (const float4*)(Wr + (size_t)(i * 256 + lane * 4 + j) * NE);
      float4 w0 = wr[0], w1 = wr[1];
      acc[0] += vs[j] * w0.x; acc[1] += vs[j] * w0.y;
      acc[2] += vs[j] * w0.z; acc[3] += vs[j] * w0.w;
      acc[4] += vs[j] * w1.x; acc[5] += vs[j] * w1.y;
      acc[6] += vs[j] * w1.z; acc[7] += vs[j] * w1.w;
    }
  }
#pragma unroll
  for (int e = 0; e < NE; ++e) {
#pragma unroll
    for (int s = 32; s > 0; s >>= 1) acc[e] += __shfl_xor(acc[e], s, 64);
  }
  if (lane == 0) {
    float lg[NE];
#pragma unroll
    for (int e = 0; e < NE; ++e) lg[e] = acc[e] + br[e];
    int a1 = 0; float m1 = lg[0];
#pragma unroll
    for (int e = 1; e < NE; ++e) if (lg[e] > m1) { m1 = lg[e]; a1 = e; }
    float m2 = -3.4e38f;
#pragma unroll
    for (int e = 0; e < NE; ++e) if (e != a1 && lg[e] > m2) m2 = lg[e];
    float g0 = 1.f / (1.f + expf(m2 - m1));
    gates[t * 2 + 0] = g0;
    gates[t * 2 + 1] = 1.f - g0;
  }
}

// ---------------- fp32 -> bf16 transpose ----------------
__global__ __launch_bounds__(256) void k_transpose(
    const float* __restrict__ in, unsigned short* __restrict__ out,
    int R, int C, int S, size_t inz, size_t outz)
{
  __shared__ float tile[32][33];
  in  += (size_t)blockIdx.z * inz;
  out += (size_t)blockIdx.z * outz;
  const int c0 = blockIdx.x * 32, r0 = blockIdx.y * 32;
  const int tx = threadIdx.x & 31, ty = threadIdx.x >> 5;
#pragma unroll
  for (int i = 0; i < 32; i += 8)
    tile[ty + i][tx] = in[(size_t)(r0 + ty + i) * C + (c0 + tx)];
  __syncthreads();
#pragma unroll
  for (int i = 0; i < 32; i += 8)
    out[(size_t)(c0 + ty + i) * S + (r0 + tx)] = f2bf(tile[tx][ty + i]);
}

// ---------------- 8-phase 256x256 MFMA GEMM (T2+T3+T4+T5) ----------------
// C[256x256 tile] = A[M][KA]·B[N][KB]^T over K = NT*64 starting at koff=z*NT*64.
// 512 threads = 8 waves (2M x 4N), per-wave 128x64, BK=64.
// LDS: 2 bufs x 4 regions {A-K0, A-K1, B-K0, B-K1} x 16 KiB = 128 KiB.
// Phase (kh, mh): 16 MFMA. One half-tile staged per phase; vmcnt(6) at ph 4/8.
// MODE 0: Hout bf16 = gate_e * relu(acc + bias[col]), e = col>>12.
// MODE 1: fp32 partial (slice 0 -> P0, slice 1 -> P1).
template<int NT, int MODE>
__global__ __launch_bounds__(512, 2) void k_gemm8(
    const unsigned short* __restrict__ A,
    const unsigned short* __restrict__ B,
    unsigned short* __restrict__ Hout,
    float* __restrict__ P0, float* __restrict__ P1,
    const float* __restrict__ bias,
    const float* __restrict__ gates,
    int KA, int KB)
{
  constexpr int NIT = NT / 2;
  __shared__ __align__(16) char lds[2 * 4 * 16384];

  const int tid = threadIdx.x;
  const int l = tid & 63, g = (l >> 4), l15 = l & 15;
  const int w = tid >> 6;
  const int wm = w >> 2, wn = w & 3;
  const int bn = blockIdx.x * 256;
  const int bm = blockIdx.y * 256;
  const int koff = blockIdx.z * (NT * 64);

  // staging source (pre-swizzled global addr, linear LDS dest):
  // dest chunk tid (+512) = (row, c); source chunk = c ^ ((row>>1)&3)
  const int srow = tid >> 2;
  const int sc = (tid & 3) ^ ((srow >> 1) & 3);
  const unsigned short* As = A + (size_t)(bm + srow) * KA + koff + sc * 8;
  const unsigned short* Bs = B + (size_t)(bn + srow) * KB + koff + sc * 8;

  auto stage = [&](int T, int reg) {  // reg: 0=A-K0 1=A-K1 2=B-K0 3=B-K1
    const unsigned short* src = ((reg >> 1) ? Bs : As) + T * 64 + (reg & 1) * 32;
    size_t rstride = (size_t)128 * ((reg >> 1) ? KB : KA);
    char* dst = lds + (((T & 1) * 4 + reg) << 14) + tid * 16;
    gl_lds16(src, dst);
    gl_lds16(src + rstride, dst + 8192);
  };

  // fragment LDS byte offsets (within a 16 KiB region; rows of 32 bf16 = 64 B)
  int aoff[2][4], boff[4];
#pragma unroll
  for (int mh = 0; mh < 2; ++mh)
#pragma unroll
    for (int mi = 0; mi < 4; ++mi) {
      int r = wm * 128 + mh * 64 + mi * 16 + l15;
      aoff[mh][mi] = r * 64 + ((g ^ ((r >> 1) & 3)) * 16);
    }
#pragma unroll
  for (int nj = 0; nj < 4; ++nj) {
    int r = wn * 64 + nj * 16 + l15;
    boff[nj] = r * 64 + ((g ^ ((r >> 1) & 3)) * 16);
  }

  f32x4 acc[8][4];
#pragma unroll
  for (int i = 0; i < 8; ++i)
#pragma unroll
    for (int j = 0; j < 4; ++j) acc[i][j] = (f32x4){0.f, 0.f, 0.f, 0.f};
  bf16x8 vb0, vb1, vb2, vb3;

  // prologue: tile0 all 4 halves + tile1 {B-K0, A-K0, B-K1}; vmcnt(6) -> tile0 landed
  stage(0, 2); stage(0, 0); stage(0, 3); stage(0, 1);
  stage(1, 2); stage(1, 0); stage(1, 3);
  asm volatile("s_waitcnt vmcnt(6)" ::: "memory");
  __builtin_amdgcn_s_barrier();

#define PH(BUF, KH, MH, VM, STG) do {                                          \
    const char* Ar_ = lds + (((BUF) * 4 + (KH)) << 14);                        \
    const char* Br_ = lds + (((BUF) * 4 + 2 + (KH)) << 14);                    \
    if ((MH) == 0) {                                                           \
      vb0 = *(const bf16x8*)(Br_ + boff[0]);                                   \
      vb1 = *(const bf16x8*)(Br_ + boff[1]);                                   \
      vb2 = *(const bf16x8*)(Br_ + boff[2]);                                   \
      vb3 = *(const bf16x8*)(Br_ + boff[3]);                                   \
    }                                                                          \
    bf16x8 va0 = *(const bf16x8*)(Ar_ + aoff[MH][0]);                          \
    bf16x8 va1 = *(const bf16x8*)(Ar_ + aoff[MH][1]);                          \
    bf16x8 va2 = *(const bf16x8*)(Ar_ + aoff[MH][2]);                          \
    bf16x8 va3 = *(const bf16x8*)(Ar_ + aoff[MH][3]);                          \
    STG;                                                                       \
    if ((VM) == 6) asm volatile("s_waitcnt vmcnt(6)" ::: "memory");            \
    else if ((VM) == 0) asm volatile("s_waitcnt vmcnt(0)" ::: "memory");       \
    __builtin_amdgcn_s_barrier();                                              \
    asm volatile("s_waitcnt lgkmcnt(0)" ::: "memory");                         \
    __builtin_amdgcn_sched_barrier(0);                                         \
    __builtin_amdgcn_s_setprio(1);                                             \
    acc[(MH)*4+0][0] = __builtin_amdgcn_mfma_f32_16x16x32_bf16(va0, vb0, acc[(MH)*4+0][0], 0,0,0); \
    acc[(MH)*4+0][1] = __builtin_amdgcn_mfma_f32_16x16x32_bf16(va0, vb1, acc[(MH)*4+0][1], 0,0,0); \
    acc[(MH)*4+0][2] = __builtin_amdgcn_mfma_f32_16x16x32_bf16(va0, vb2, acc[(MH)*4+0][2], 0,0,0); \
    acc[(MH)*4+0][3] = __builtin_amdgcn_mfma_f32_16x16x32_bf16(va0, vb3, acc[(MH)*4+0][3], 0,0,0); \
    acc[(MH)*4+1][0] = __builtin_amdgcn_mfma_f32_16x16x32_bf16(va1, vb0, acc[(MH)*4+1][0], 0,0,0); \
    acc[(MH)*4+1][1] = __builtin_amdgcn_mfma_f32_16x16x32_bf16(va1, vb1, acc[(MH)*4+1][1], 0,0,0); \
    acc[(MH)*4+1][2] = __builtin_amdgcn_mfma_f32_16x16x32_bf16(va1, vb2, acc[(MH)*4+1][2], 0,0,0); \
    acc[(MH)*4+1][3] = __builtin_amdgcn_mfma_f32_16x16x32_bf16(va1, vb3, acc[(MH)*4+1][3], 0,0,0); \
    acc[(MH)*4+2][0] = __builtin_amdgcn_mfma_f32_16x16x32_bf16(va2, vb0, acc[(MH)*4+2][0], 0,0,0); \
    acc[(MH)*4+2][1] = __builtin_amdgcn_mfma_f32_16x16x32_bf16(va2, vb1, acc[(MH)*4+2][1], 0,0,0); \
    acc[(MH)*4+2][2] = __builtin_amdgcn_mfma_f32_16x16x32_bf16(va2, vb2, acc[(MH)*4+2][2], 0,0,0); \
    acc[(MH)*4+2][3] = __builtin_amdgcn_mfma_f32_16x16x32_bf16(va2, vb3, acc[(MH)*4+2][3], 0,0,0); \
    acc[(MH)*4+3][0] = __builtin_amdgcn_mfma_f32_16x16x32_bf16(va3, vb0, acc[(MH)*4+3][0], 0,0,0); \
    acc[(MH)*4+3][1] = __builtin_amdgcn_mfma_f32_16x16x32_bf16(va3, vb1, acc[(MH)*4+3][1], 0,0,0); \
    acc[(MH)*4+3][2] = __builtin_amdgcn_mfma_f32_16x16x32_bf16(va3, vb2, acc[(MH)*4+3][2], 0,0,0); \
    acc[(MH)*4+3][3] = __builtin_amdgcn_mfma_f32_16x16x32_bf16(va3, vb3, acc[(MH)*4+3][3], 0,0,0); \
    __builtin_amdgcn_s_setprio(0);                                             \
    __builtin_amdgcn_s_barrier();                                              \
  } while (0)

  for (int t = 0; t < NIT - 1; ++t) {
    PH(0, 0, 0, -1, stage(2 * t + 1, 1));
    PH(0, 0, 1, -1, stage(2 * t + 2, 2));
    PH(0, 1, 0, -1, stage(2 * t + 2, 0));
    PH(0, 1, 1,  6, stage(2 * t + 2, 3));
    PH(1, 0, 0, -1, stage(2 * t + 2, 1));
    PH(1, 0, 1, -1, stage(2 * t + 3, 2));
    PH(1, 1, 0, -1, stage(2 * t + 3, 0));
    PH(1, 1, 1,  6, stage(2 * t + 3, 3));
  }
  // final iteration: only the odd tile's A-K1 remains to stage
  PH(0, 0, 0, -1, stage(NT - 1, 1));
  PH(0, 0, 1, -1, ;);
  PH(0, 1, 0, -1, ;);
  PH(0, 1, 1,  0, ;);
  PH(1, 0, 0, -1, ;);
  PH(1, 0, 1, -1, ;);
  PH(1, 1, 0, -1, ;);
  PH(1, 1, 1, -1, ;);
#undef PH

  // epilogue; C/D map: col = l&15, row = (l>>4)*4 + rr
  if constexpr (MODE == 0) {
    const int ge = bn >> 12;
    float bcol[4];
#pragma unroll
    for (int nj = 0; nj < 4; ++nj) bcol[nj] = bias[bn + wn * 64 + nj * 16 + l15];
#pragma unroll
    for (int mi = 0; mi < 8; ++mi) {
#pragma unroll
      for (int rr = 0; rr < 4; ++rr) {
        int row = bm + wm * 128 + mi * 16 + g * 4 + rr;
        float gate = gates[row * 2 + ge];
        size_t rb = (size_t)row * KCAT + bn + wn * 64 + l15;
#pragma unroll
        for (int nj = 0; nj < 4; ++nj) {
          float v = acc[mi][nj][rr] + bcol[nj];
          Hout[rb + nj * 16] = f2bf(fmaxf(v, 0.f) * gate);
        }
      }
    }
  } else {
    float* P = blockIdx.z ? P1 : P0;
#pragma unroll
    for (int mi = 0; mi < 8; ++mi) {
#pragma unroll
      for (int rr = 0; rr < 4; ++rr) {
        int row = bm + wm * 128 + mi * 16 + g * 4 + rr;
        size_t rb = (size_t)row * DDIM + bn + wn * 64 + l15;
#pragma unroll
        for (int nj = 0; nj < 4; ++nj) P[rb + nj * 16] = acc[mi][nj][rr];
      }
    }
  }
}

// ---------------- combine: out = p0 + p1 + g0*b2[0] + g1*b2[1] ----------------
__global__ __launch_bounds__(256) void k_combine(
    const float* __restrict__ P1, const float* __restrict__ b2,
    const float* __restrict__ gates, float* __restrict__ O)
{
  size_t i = ((size_t)blockIdx.x * 256 + threadIdx.x) * 4;
  int row = (int)(i >> 10), d = (int)(i & 1023);
  float g0 = gates[row * 2], g1 = gates[row * 2 + 1];
  float4 p0 = *(const float4*)(O + i);
  float4 p1 = *(const float4*)(P1 + i);
  float4 ba = *(const float4*)(b2 + d);
  float4 bb = *(const float4*)(b2 + DDIM + d);
  float4 r;
  r.x = p0.x + p1.x + g0 * ba.x + g1 * bb.x;
  r.y = p0.y + p1.y + g0 * ba.y + g1 * bb.y;
  r.z = p0.z + p1.z + g0 * ba.z + g1 * bb.z;
  r.w = p0.w + p1.w + g0 * ba.w + g1 * bb.w;
  *(float4*)(O + i) = r;
}

extern "C" void kernel_launch(void* const* d_in, const int* in_sizes, int n_in,
                              void* d_out, int out_size, void* d_ws, size_t ws_size,
                              hipStream_t stream) {
  const float* x  = (const float*)d_in[0];
  const float* Wr = (const float*)d_in[1];
  const float* br = (const float*)d_in[2];
  const float* W1 = (const float*)d_in[3];
  const float* b1 = (const float*)d_in[4];
  const float* W2 = (const float*)d_in[5];
  const float* b2 = (const float*)d_in[6];

  char* ws = (char*)d_ws;
  unsigned short* xb    = (unsigned short*)(ws);               // [0,16M)  x bf16
  unsigned short* W1T   = (unsigned short*)(ws + (16u << 20)); // [16,32M) [8192][1024]
  unsigned short* W2T   = (unsigned short*)(ws + (32u << 20)); // [32,48M) [1024][8192]
  float*          gates = (float*)(ws + (48u << 20));          // [48M,+64K)
  unsigned short* hbuf  = (unsigned short*)(ws + (49u << 20)); // [49,177M) [8192][8192]
  float*          P1    = (float*)(ws);                        // reuses xb+W1T after GEMM1

  k_router<<<dim3(T_TOK / 4), dim3(256), 0, stream>>>(x, Wr, br, xb, gates);

  k_transpose<<<dim3(HDIM / 32, DDIM / 32, 2), dim3(256), 0, stream>>>(
      W1, W1T, DDIM, HDIM, DDIM, (size_t)DDIM * HDIM, (size_t)HDIM * DDIM);
  k_transpose<<<dim3(DDIM / 32, HDIM / 32, 2), dim3(256), 0, stream>>>(
      W2, W2T, HDIM, DDIM, KCAT, (size_t)HDIM * DDIM, (size_t)HDIM);

  // layer1: 8192x8192x1024 (experts concat over N)
  k_gemm8<16, 0><<<dim3(KCAT / 256, T_TOK / 256, 1), dim3(512), 0, stream>>>(
      xb, W1T, hbuf, nullptr, nullptr, b1, gates, DDIM, DDIM);

  // layer2: 8192x1024x8192, split-K=2 at the expert boundary
  k_gemm8<64, 1><<<dim3(DDIM / 256, T_TOK / 256, 2), dim3(512), 0, stream>>>(
      hbuf, W2T, nullptr, (float*)d_out, P1, nullptr, nullptr, KCAT, KCAT);

  k_combine<<<dim3(T_TOK * DDIM / 4 / 256), dim3(256), 0, stream>>>(
      P1, b2, gates, (float*)d_out);
}

// Round 4
// 318.986 us; speedup vs baseline: 1.4501x; 1.0440x over previous
//
#include <hip/hip_runtime.h>
#include <hip/hip_bf16.h>

#define T_TOK 8192
#define DDIM  1024
#define HDIM  4096
#define KCAT  8192   // 2*HDIM
#define NE    8

typedef __attribute__((ext_vector_type(8))) __bf16 bf16x8;
typedef __attribute__((ext_vector_type(4))) float  f32x4;

__device__ __forceinline__ unsigned short f2bf(float f) {
  union { float f; unsigned u; } v; v.f = f;
  unsigned r = v.u + 0x7fffu + ((v.u >> 16) & 1u);
  return (unsigned short)(r >> 16);
}

__device__ __forceinline__ void gl_lds16(const unsigned short* g, char* l) {
  __builtin_amdgcn_global_load_lds(
      (__attribute__((address_space(1))) const void*)g,
      (__attribute__((address_space(3))) void*)l,
      16, 0, 0);
}

// ---------------- router + x -> bf16 conversion ----------------
__global__ __launch_bounds__(256) void k_router(
    const float* __restrict__ x, const float* __restrict__ Wr,
    const float* __restrict__ br, unsigned short* __restrict__ xb,
    float* __restrict__ gates)
{
  const int lane = threadIdx.x & 63;
  const int wv   = threadIdx.x >> 6;
  const int t    = blockIdx.x * 4 + wv;
  const float* xr = x + (size_t)t * DDIM;
  unsigned short* xo = xb + (size_t)t * DDIM;

  float acc[NE];
#pragma unroll
  for (int e = 0; e < NE; ++e) acc[e] = 0.f;

#pragma unroll
  for (int i = 0; i < 4; ++i) {
    float4 v = *(const float4*)(xr + i * 256 + lane * 4);
    ushort4 o;
    o.x = f2bf(v.x); o.y = f2bf(v.y); o.z = f2bf(v.z); o.w = f2bf(v.w);
    *(ushort4*)(xo + i * 256 + lane * 4) = o;
    float vs[4] = {v.x, v.y, v.z, v.w};
#pragma unroll
    for (int j = 0; j < 4; ++j) {
      const float4* wr = (const float4*)(Wr + (size_t)(i * 256 + lane * 4 + j) * NE);
      float4 w0 = wr[0], w1 = wr[1];
      acc[0] += vs[j] * w0.x; acc[1] += vs[j] * w0.y;
      acc[2] += vs[j] * w0.z; acc[3] += vs[j] * w0.w;
      acc[4] += vs[j] * w1.x; acc[5] += vs[j] * w1.y;
      acc[6] += vs[j] * w1.z; acc[7] += vs[j] * w1.w;
    }
  }
#pragma unroll
  for (int e = 0; e < NE; ++e) {
#pragma unroll
    for (int s = 32; s > 0; s >>= 1) acc[e] += __shfl_xor(acc[e], s, 64);
  }
  if (lane == 0) {
    float lg[NE];
#pragma unroll
    for (int e = 0; e < NE; ++e) lg[e] = acc[e] + br[e];
    int a1 = 0; float m1 = lg[0];
#pragma unroll
    for (int e = 1; e < NE; ++e) if (lg[e] > m1) { m1 = lg[e]; a1 = e; }
    float m2 = -3.4e38f;
#pragma unroll
    for (int e = 0; e < NE; ++e) if (e != a1 && lg[e] > m2) m2 = lg[e];
    float g0 = 1.f / (1.f + expf(m2 - m1));
    gates[t * 2 + 0] = g0;
    gates[t * 2 + 1] = 1.f - g0;
  }
}

// ---------------- fp32 -> bf16 transpose ----------------
__global__ __launch_bounds__(256) void k_transpose(
    const float* __restrict__ in, unsigned short* __restrict__ out,
    int R, int C, int S, size_t inz, size_t outz)
{
  __shared__ float tile[32][33];
  in  += (size_t)blockIdx.z * inz;
  out += (size_t)blockIdx.z * outz;
  const int c0 = blockIdx.x * 32, r0 = blockIdx.y * 32;
  const int tx = threadIdx.x & 31, ty = threadIdx.x >> 5;
#pragma unroll
  for (int i = 0; i < 32; i += 8)
    tile[ty + i][tx] = in[(size_t)(r0 + ty + i) * C + (c0 + tx)];
  __syncthreads();
#pragma unroll
  for (int i = 0; i < 32; i += 8)
    out[(size_t)(c0 + ty + i) * S + (r0 + tx)] = f2bf(tile[tx][ty + i]);
}

// ---------------- 8-phase 256x256 MFMA GEMM (T1+T2+T3+T4+T5) ----------------
// C[256x256 tile] = A[M][KA]·B[N][KB]^T over K = NT*64 starting at koff=z*NT*64.
// 512 threads = 8 waves (2M x 4N), per-wave 128x64, BK=64.
// LDS: 2 bufs x 4 regions {A-K0, A-K1, B-K0, B-K1} x 16 KiB = 128 KiB.
// Phase (kh, mh): 16 MFMA. One half-tile staged per phase; vmcnt(6) at ph 4/8.
// XCD swizzle (T1): bijective remap of the linear dispatch id so each XCD's
// resident blocks form a 2D chunk with L2-resident operand panels.
// MODE 0: Hout bf16 = gate_e * relu(acc + bias[col]), e = col>>12.
// MODE 1: fp32 partial (slice 0 -> P0, slice 1 -> P1).
template<int NT, int MODE>
__global__ __launch_bounds__(512, 2) void k_gemm8(
    const unsigned short* __restrict__ A,
    const unsigned short* __restrict__ B,
    unsigned short* __restrict__ Hout,
    float* __restrict__ P0, float* __restrict__ P1,
    const float* __restrict__ bias,
    const float* __restrict__ gates,
    int KA, int KB)
{
  constexpr int NIT = NT / 2;
  __shared__ __align__(16) char lds[2 * 4 * 16384];

  const int tid = threadIdx.x;
  const int l = tid & 63, g = (l >> 4), l15 = l & 15;
  const int w = tid >> 6;
  const int wm = w >> 2, wn = w & 3;

  // ---- XCD-chunked bijective swizzle ----
  int bmIdx, bnIdx, bzIdx;
  {
    int lin = ((blockIdx.z * gridDim.y) + blockIdx.y) * gridDim.x + blockIdx.x;
    int xcd = lin & 7, slot = (lin >> 3) & 31;
    if (MODE == 0) {
      // grid 32x32, 4 temporal rounds; XCD owns fixed 4-wide N strip.
      int r = lin >> 8;
      bmIdx = r * 8 + (slot >> 2);
      bnIdx = xcd * 4 + (slot & 3);
      bzIdx = 0;
    } else {
      // grid 4x32x2, one round; XCD owns one z slice x 8 M panels x all N.
      bzIdx = xcd & 1;
      bmIdx = (xcd >> 1) * 8 + (slot >> 2);
      bnIdx = slot & 3;
    }
  }
  const int bn = bnIdx * 256;
  const int bm = bmIdx * 256;
  const int koff = bzIdx * (NT * 64);

  // staging source (pre-swizzled global addr, linear LDS dest):
  // dest chunk tid (+512) = (row, c); source chunk = c ^ ((row>>1)&3)
  const int srow = tid >> 2;
  const int sc = (tid & 3) ^ ((srow >> 1) & 3);
  const unsigned short* As = A + (size_t)(bm + srow) * KA + koff + sc * 8;
  const unsigned short* Bs = B + (size_t)(bn + srow) * KB + koff + sc * 8;

  auto stage = [&](int T, int reg) {  // reg: 0=A-K0 1=A-K1 2=B-K0 3=B-K1
    const unsigned short* src = ((reg >> 1) ? Bs : As) + T * 64 + (reg & 1) * 32;
    size_t rstride = (size_t)128 * ((reg >> 1) ? KB : KA);
    char* dst = lds + (((T & 1) * 4 + reg) << 14) + tid * 16;
    gl_lds16(src, dst);
    gl_lds16(src + rstride, dst + 8192);
  };

  // fragment LDS byte offsets (within a 16 KiB region; rows of 32 bf16 = 64 B)
  int aoff[2][4], boff[4];
#pragma unroll
  for (int mh = 0; mh < 2; ++mh)
#pragma unroll
    for (int mi = 0; mi < 4; ++mi) {
      int r = wm * 128 + mh * 64 + mi * 16 + l15;
      aoff[mh][mi] = r * 64 + ((g ^ ((r >> 1) & 3)) * 16);
    }
#pragma unroll
  for (int nj = 0; nj < 4; ++nj) {
    int r = wn * 64 + nj * 16 + l15;
    boff[nj] = r * 64 + ((g ^ ((r >> 1) & 3)) * 16);
  }

  f32x4 acc[8][4];
#pragma unroll
  for (int i = 0; i < 8; ++i)
#pragma unroll
    for (int j = 0; j < 4; ++j) acc[i][j] = (f32x4){0.f, 0.f, 0.f, 0.f};
  bf16x8 vb0, vb1, vb2, vb3;

  // prologue: tile0 all 4 halves + tile1 {B-K0, A-K0, B-K1}; vmcnt(6) -> tile0 landed
  stage(0, 2); stage(0, 0); stage(0, 3); stage(0, 1);
  stage(1, 2); stage(1, 0); stage(1, 3);
  asm volatile("s_waitcnt vmcnt(6)" ::: "memory");
  __builtin_amdgcn_s_barrier();

#define PH(BUF, KH, MH, VM, STG) do {                                          \
    const char* Ar_ = lds + (((BUF) * 4 + (KH)) << 14);                        \
    const char* Br_ = lds + (((BUF) * 4 + 2 + (KH)) << 14);                    \
    if ((MH) == 0) {                                                           \
      vb0 = *(const bf16x8*)(Br_ + boff[0]);                                   \
      vb1 = *(const bf16x8*)(Br_ + boff[1]);                                   \
      vb2 = *(const bf16x8*)(Br_ + boff[2]);                                   \
      vb3 = *(const bf16x8*)(Br_ + boff[3]);                                   \
    }                                                                          \
    bf16x8 va0 = *(const bf16x8*)(Ar_ + aoff[MH][0]);                          \
    bf16x8 va1 = *(const bf16x8*)(Ar_ + aoff[MH][1]);                          \
    bf16x8 va2 = *(const bf16x8*)(Ar_ + aoff[MH][2]);                          \
    bf16x8 va3 = *(const bf16x8*)(Ar_ + aoff[MH][3]);                          \
    STG;                                                                       \
    if ((VM) == 6) asm volatile("s_waitcnt vmcnt(6)" ::: "memory");            \
    else if ((VM) == 0) asm volatile("s_waitcnt vmcnt(0)" ::: "memory");       \
    __builtin_amdgcn_s_barrier();                                              \
    asm volatile("s_waitcnt lgkmcnt(0)" ::: "memory");                         \
    __builtin_amdgcn_sched_barrier(0);                                         \
    __builtin_amdgcn_s_setprio(1);                                             \
    acc[(MH)*4+0][0] = __builtin_amdgcn_mfma_f32_16x16x32_bf16(va0, vb0, acc[(MH)*4+0][0], 0,0,0); \
    acc[(MH)*4+0][1] = __builtin_amdgcn_mfma_f32_16x16x32_bf16(va0, vb1, acc[(MH)*4+0][1], 0,0,0); \
    acc[(MH)*4+0][2] = __builtin_amdgcn_mfma_f32_16x16x32_bf16(va0, vb2, acc[(MH)*4+0][2], 0,0,0); \
    acc[(MH)*4+0][3] = __builtin_amdgcn_mfma_f32_16x16x32_bf16(va0, vb3, acc[(MH)*4+0][3], 0,0,0); \
    acc[(MH)*4+1][0] = __builtin_amdgcn_mfma_f32_16x16x32_bf16(va1, vb0, acc[(MH)*4+1][0], 0,0,0); \
    acc[(MH)*4+1][1] = __builtin_amdgcn_mfma_f32_16x16x32_bf16(va1, vb1, acc[(MH)*4+1][1], 0,0,0); \
    acc[(MH)*4+1][2] = __builtin_amdgcn_mfma_f32_16x16x32_bf16(va1, vb2, acc[(MH)*4+1][2], 0,0,0); \
    acc[(MH)*4+1][3] = __builtin_amdgcn_mfma_f32_16x16x32_bf16(va1, vb3, acc[(MH)*4+1][3], 0,0,0); \
    acc[(MH)*4+2][0] = __builtin_amdgcn_mfma_f32_16x16x32_bf16(va2, vb0, acc[(MH)*4+2][0], 0,0,0); \
    acc[(MH)*4+2][1] = __builtin_amdgcn_mfma_f32_16x16x32_bf16(va2, vb1, acc[(MH)*4+2][1], 0,0,0); \
    acc[(MH)*4+2][2] = __builtin_amdgcn_mfma_f32_16x16x32_bf16(va2, vb2, acc[(MH)*4+2][2], 0,0,0); \
    acc[(MH)*4+2][3] = __builtin_amdgcn_mfma_f32_16x16x32_bf16(va2, vb3, acc[(MH)*4+2][3], 0,0,0); \
    acc[(MH)*4+3][0] = __builtin_amdgcn_mfma_f32_16x16x32_bf16(va3, vb0, acc[(MH)*4+3][0], 0,0,0); \
    acc[(MH)*4+3][1] = __builtin_amdgcn_mfma_f32_16x16x32_bf16(va3, vb1, acc[(MH)*4+3][1], 0,0,0); \
    acc[(MH)*4+3][2] = __builtin_amdgcn_mfma_f32_16x16x32_bf16(va3, vb2, acc[(MH)*4+3][2], 0,0,0); \
    acc[(MH)*4+3][3] = __builtin_amdgcn_mfma_f32_16x16x32_bf16(va3, vb3, acc[(MH)*4+3][3], 0,0,0); \
    __builtin_amdgcn_s_setprio(0);                                             \
    __builtin_amdgcn_s_barrier();                                              \
  } while (0)

  for (int t = 0; t < NIT - 1; ++t) {
    PH(0, 0, 0, -1, stage(2 * t + 1, 1));
    PH(0, 0, 1, -1, stage(2 * t + 2, 2));
    PH(0, 1, 0, -1, stage(2 * t + 2, 0));
    PH(0, 1, 1,  6, stage(2 * t + 2, 3));
    PH(1, 0, 0, -1, stage(2 * t + 2, 1));
    PH(1, 0, 1, -1, stage(2 * t + 3, 2));
    PH(1, 1, 0, -1, stage(2 * t + 3, 0));
    PH(1, 1, 1,  6, stage(2 * t + 3, 3));
  }
  // final iteration: only the odd tile's A-K1 remains to stage
  PH(0, 0, 0, -1, stage(NT - 1, 1));
  PH(0, 0, 1, -1, ;);
  PH(0, 1, 0, -1, ;);
  PH(0, 1, 1,  0, ;);
  PH(1, 0, 0, -1, ;);
  PH(1, 0, 1, -1, ;);
  PH(1, 1, 0, -1, ;);
  PH(1, 1, 1, -1, ;);
#undef PH

  // epilogue; C/D map: col = l&15, row = (l>>4)*4 + rr
  if constexpr (MODE == 0) {
    const int ge = bn >> 12;
    float bcol[4];
#pragma unroll
    for (int nj = 0; nj < 4; ++nj) bcol[nj] = bias[bn + wn * 64 + nj * 16 + l15];
#pragma unroll
    for (int mi = 0; mi < 8; ++mi) {
#pragma unroll
      for (int rr = 0; rr < 4; ++rr) {
        int row = bm + wm * 128 + mi * 16 + g * 4 + rr;
        float gate = gates[row * 2 + ge];
        size_t rb = (size_t)row * KCAT + bn + wn * 64 + l15;
#pragma unroll
        for (int nj = 0; nj < 4; ++nj) {
          float v = acc[mi][nj][rr] + bcol[nj];
          Hout[rb + nj * 16] = f2bf(fmaxf(v, 0.f) * gate);
        }
      }
    }
  } else {
    float* P = bzIdx ? P1 : P0;
#pragma unroll
    for (int mi = 0; mi < 8; ++mi) {
#pragma unroll
      for (int rr = 0; rr < 4; ++rr) {
        int row = bm + wm * 128 + mi * 16 + g * 4 + rr;
        size_t rb = (size_t)row * DDIM + bn + wn * 64 + l15;
#pragma unroll
        for (int nj = 0; nj < 4; ++nj) P[rb + nj * 16] = acc[mi][nj][rr];
      }
    }
  }
}

// ---------------- combine: out = p0 + p1 + g0*b2[0] + g1*b2[1] ----------------
__global__ __launch_bounds__(256) void k_combine(
    const float* __restrict__ P1, const float* __restrict__ b2,
    const float* __restrict__ gates, float* __restrict__ O)
{
  size_t i = ((size_t)blockIdx.x * 256 + threadIdx.x) * 4;
  int row = (int)(i >> 10), d = (int)(i & 1023);
  float g0 = gates[row * 2], g1 = gates[row * 2 + 1];
  float4 p0 = *(const float4*)(O + i);
  float4 p1 = *(const float4*)(P1 + i);
  float4 ba = *(const float4*)(b2 + d);
  float4 bb = *(const float4*)(b2 + DDIM + d);
  float4 r;
  r.x = p0.x + p1.x + g0 * ba.x + g1 * bb.x;
  r.y = p0.y + p1.y + g0 * ba.y + g1 * bb.y;
  r.z = p0.z + p1.z + g0 * ba.z + g1 * bb.z;
  r.w = p0.w + p1.w + g0 * ba.w + g1 * bb.w;
  *(float4*)(O + i) = r;
}

extern "C" void kernel_launch(void* const* d_in, const int* in_sizes, int n_in,
                              void* d_out, int out_size, void* d_ws, size_t ws_size,
                              hipStream_t stream) {
  const float* x  = (const float*)d_in[0];
  const float* Wr = (const float*)d_in[1];
  const float* br = (const float*)d_in[2];
  const float* W1 = (const float*)d_in[3];
  const float* b1 = (const float*)d_in[4];
  const float* W2 = (const float*)d_in[5];
  const float* b2 = (const float*)d_in[6];

  char* ws = (char*)d_ws;
  unsigned short* xb    = (unsigned short*)(ws);               // [0,16M)  x bf16
  unsigned short* W1T   = (unsigned short*)(ws + (16u << 20)); // [16,32M) [8192][1024]
  unsigned short* W2T   = (unsigned short*)(ws + (32u << 20)); // [32,48M) [1024][8192]
  float*          gates = (float*)(ws + (48u << 20));          // [48M,+64K)
  unsigned short* hbuf  = (unsigned short*)(ws + (49u << 20)); // [49,177M) [8192][8192]
  float*          P1    = (float*)(ws);                        // reuses xb+W1T after GEMM1

  k_router<<<dim3(T_TOK / 4), dim3(256), 0, stream>>>(x, Wr, br, xb, gates);

  k_transpose<<<dim3(HDIM / 32, DDIM / 32, 2), dim3(256), 0, stream>>>(
      W1, W1T, DDIM, HDIM, DDIM, (size_t)DDIM * HDIM, (size_t)HDIM * DDIM);
  k_transpose<<<dim3(DDIM / 32, HDIM / 32, 2), dim3(256), 0, stream>>>(
      W2, W2T, HDIM, DDIM, KCAT, (size_t)HDIM * DDIM, (size_t)HDIM);

  // layer1: 8192x8192x1024 (experts concat over N)
  k_gemm8<16, 0><<<dim3(KCAT / 256, T_TOK / 256, 1), dim3(512), 0, stream>>>(
      xb, W1T, hbuf, nullptr, nullptr, b1, gates, DDIM, DDIM);

  // layer2: 8192x1024x8192, split-K=2 at the expert boundary
  k_gemm8<64, 1><<<dim3(DDIM / 256, T_TOK / 256, 2), dim3(512), 0, stream>>>(
      hbuf, W2T, nullptr, (float*)d_out, P1, nullptr, nullptr, KCAT, KCAT);

  k_combine<<<dim3(T_TOK * DDIM / 4 / 256), dim3(256), 0, stream>>>(
      P1, b2, gates, (float*)d_out);
}